// Round 6
// baseline (178.838 us; speedup 1.0000x reference)
//
#include <hip/hip_runtime.h>
#include <stdint.h>

// VectorQuantizer on MI355X (gfx950) — round 12
// inputs: x [64,256,32,32] fp32 (NCHW), codebook [1024,256] fp32
// outputs: q_st [64,256,32,32] fp32, loss scalar
//
// R12 restructure: x STATIONARY in registers, codebook STREAMED via LDS dbuf.
// 512 blocks x 4 waves; wave owns 32 hw rows (16 B-frags global->reg, f2bf
// in-register, loaded once — AGPR parking OK) and sweeps ALL 1024 codes; the
// 4 waves share each 16 KB A m-tile staged by global_load_lds(16B) into a
// 2x16KB double-buffer (A L2 traffic /4 vs R6; K-loop memory = ds_read only).
// One barrier per m-tile (m97 pattern) at 2 blocks/CU (R8's failure was 1).
// LDS exactly 32 KB (sfin overlaid post-loop) — fits 2 blocks under the
// 128KB-usable quantization R11 exposed. launch_bounds(256,2): no reg pressure
// (R10's failure). Wave owns rows end-to-end: no cross-wave argmax merge.

#define DIM 256
#define AS1 __attribute__((address_space(1)))
#define AS3 __attribute__((address_space(3)))

typedef __attribute__((ext_vector_type(8)))  short bf16x8_t;   // MFMA A/B frag (4 VGPRs)
typedef __attribute__((ext_vector_type(4)))  float f32x4_t;
typedef __attribute__((ext_vector_type(16))) float f32x16_t;   // 32x32 C/D frag

__device__ __forceinline__ uint32_t f2bf(float f) {
    union { float f; uint32_t u; } v; v.f = f;
    uint32_t r = v.u + 0x7FFFu + ((v.u >> 16) & 1u);   // RNE
    return r >> 16;
}

// ---- prep: one wave per code. Emits (a) bf16 codebook in exact MFMA A-frag
// order: entry e=(mt*16+ks)*64+lane2 holds cb[mt*32+(lane2&31)][ks*16+(lane2>>5)*8+j],
// and (b) -0.5*||c||^2 in C/D-register order (nh_ord[mt*32 + half*16 + r]).
__global__ __launch_bounds__(256) void vq_prep(const float* __restrict__ cb,
                                               char* __restrict__ cbsw,
                                               float* __restrict__ nh_ord) {
    const int code = blockIdx.x * 4 + (threadIdx.x >> 6);
    const int l    = threadIdx.x & 63;               // holds d = 4l..4l+3
    const f32x4_t v = ((const f32x4_t*)(cb + code * DIM))[l];
    float sq = v.x * v.x + v.y * v.y + v.z * v.z + v.w * v.w;

    const int mt = code >> 5;
    const int ks = l >> 2;               // d/16
    const int hl = (l >> 1) & 1;         // (d%16)/8
    const uint32_t ebyte = (uint32_t)(((mt * 16 + ks) * 64 + (code & 31) + 32 * hl) * 16
                                      + (l & 1) * 8);
    uint2 o;
    o.x = f2bf(v.x) | (f2bf(v.y) << 16);
    o.y = f2bf(v.z) | (f2bf(v.w) << 16);
    *(uint2*)(cbsw + ebyte) = o;

    #pragma unroll
    for (int m = 32; m; m >>= 1) sq += __shfl_xor(sq, m);
    if (l == 0) {
        const int rw = code & 31;
        const int h4 = (rw >> 2) & 1;
        const int r  = (rw & 3) | ((rw >> 3) << 2);
        nh_ord[mt * 32 + h4 * 16 + r] = -0.5f * sq;
    }
}

// ---- main: 512 blocks x 256 threads; block = 128 hw rows; wave w owns rows
// w*32..w*32+31 and sweeps all 1024 codes (32 m-tiles through the LDS dbuf).
__global__ __launch_bounds__(256, 2) void vq_main(const float* __restrict__ x,
                                                  const float* __restrict__ cb,
                                                  const char* __restrict__ cbsw,
                                                  const float* __restrict__ nh_ord,
                                                  float* __restrict__ out,
                                                  float* __restrict__ loss_accum) {
    // 32 KB exactly: A double-buffer [2][16KB] during K-loop; sfin afterwards.
    __shared__ __align__(16) uint32_t shm[8192];

    const int t    = threadIdx.x;
    const int w    = t >> 6;
    const int lane = t & 63;
    const int col  = lane & 31;          // row within wave's 32
    const int hi   = lane >> 5;          // k-half (d-octet selector)
    const int n0   = blockIdx.x * 128;
    const int batch = n0 >> 10;
    const int hw0   = n0 & 1023;

    // ---- issue A m-tile 0 into buf0 now; latency hides under the x load.
    {
        const char* s = cbsw + (size_t)(w * 1024 + lane * 16);
        #pragma unroll
        for (int q = 0; q < 4; ++q)
            __builtin_amdgcn_global_load_lds(
                (const AS1 uint32_t*)(s + q * 4096),
                (AS3 uint32_t*)(shm + q * 1024 + w * 256),   // +lane*16B by HW
                16, 0, 0);
    }

    // ---- x -> breg direct (no LDS round-trip). Lane holds rows w*32+col,
    // d = ks*16 + hi*8 + j. Per (ks,j) scalar load: lanes 0-31 = 128B segment,
    // lanes 32-63 = the d+8 segment. Also accumulates ||x||^2.
    float sq = 0.f;
    bf16x8_t breg[16];
    {
        const float* xp = x + (size_t)batch * (DIM * 1024) + (size_t)hi * 8 * 1024
                            + hw0 + w * 32 + col;
        #pragma unroll
        for (int ks = 0; ks < 16; ++ks) {
            const float* dp = xp + (size_t)ks * 16 * 1024;
            float a[8];
            #pragma unroll
            for (int j = 0; j < 8; ++j) {
                a[j] = dp[(size_t)j * 1024];
                sq += a[j] * a[j];
            }
            uint4 pk;
            pk.x = f2bf(a[0]) | (f2bf(a[1]) << 16);
            pk.y = f2bf(a[2]) | (f2bf(a[3]) << 16);
            pk.z = f2bf(a[4]) | (f2bf(a[5]) << 16);
            pk.w = f2bf(a[6]) | (f2bf(a[7]) << 16);
            union { uint4 u; bf16x8_t v; } cv; cv.u = pk;
            breg[ks] = cv.v;
        }
        // lane pairs (l, l^32) cover disjoint d-halves of the same row:
        // full-wave reduce = sum ||x_row||^2 over this wave's 32 rows.
        #pragma unroll
        for (int m = 32; m; m >>= 1) sq += __shfl_xor(sq, m);
    }
    __syncthreads();   // drains vmcnt: buf0 staged, all waves ready

    // ---- K-loop: 32 m-tiles; A from LDS dbuf (shared by all 4 waves),
    // B stationary in regs; one barrier per tile.
    float best = -3.0e38f;
    int   bi = 0;

    #pragma unroll 1
    for (int mt = 0; mt < 32; ++mt) {
        const uint32_t* cur = shm + (mt & 1) * 4096;

        // prefetch next m-tile into the other half (in flight across the MFMAs)
        if (mt < 31) {
            const char* s = cbsw + (size_t)(mt + 1) * 16384 + w * 1024 + lane * 16;
            uint32_t* db = shm + ((mt + 1) & 1) * 4096;
            #pragma unroll
            for (int q = 0; q < 4; ++q)
                __builtin_amdgcn_global_load_lds(
                    (const AS1 uint32_t*)(s + q * 4096),
                    (AS3 uint32_t*)(db + q * 1024 + w * 256),
                    16, 0, 0);
        }

        const f32x4_t* nhp = (const f32x4_t*)(nh_ord + mt * 32 + hi * 16);
        const f32x4_t h0 = nhp[0], h1 = nhp[1], h2 = nhp[2], h3 = nhp[3];
        f32x16_t acc;
        #pragma unroll
        for (int r = 0; r < 4; ++r) {
            acc[r] = h0[r]; acc[4 + r] = h1[r]; acc[8 + r] = h2[r]; acc[12 + r] = h3[r];
        }
        #pragma unroll
        for (int ks = 0; ks < 16; ++ks) {
            const bf16x8_t a = *(const bf16x8_t*)(cur + ks * 256 + lane * 4);
            acc = __builtin_amdgcn_mfma_f32_32x32x16_bf16(a, breg[ks], acc, 0, 0, 0);
        }

        // scan: codes in increasing order; strict > keeps the lowest index
        #pragma unroll
        for (int r = 0; r < 16; ++r) {
            const int code = mt * 32 + hi * 4 + ((r & 3) + 8 * (r >> 2));
            if (acc[r] > best) { best = acc[r]; bi = code; }
        }
        __syncthreads();   // next buffer staged + everyone done with cur
    }

    // ---- combine lane pairs (same row, disjoint code subsets) -> row best-of-1024
    {
        const float ov = __shfl_xor(best, 32);
        const int   oi = __shfl_xor(bi, 32);
        if (ov > best || (ov == best && oi < bi)) { best = ov; bi = oi; }
    }

    // ---- publish indices into shm (A-dbuf is dead; overlay sfin)
    int* sfin = (int*)shm;
    if (lane < 32) sfin[w * 32 + lane] = bi;

    // ---- per-wave loss partial: lane pairs duplicate each row's best, so
    // sum(-best) over 64 lanes = -2*sum_rows(score); sq adds ||x||^2.
    {
        float ls = -best;
        #pragma unroll
        for (int m = 32; m; m >>= 1) ls += __shfl_xor(ls, m);
        if (lane == 0) atomicAdd(loss_accum, ls + sq);
    }
    __syncthreads();

    // ---- epilogue: gather fp32 codebook rows, dwordx4 stores along hw
    {
        const int q  = t & 31;     // rows 4q..4q+3 of 128
        const int dg = t >> 5;     // 0..7 -> d in [dg*32, dg*32+32)
        const int c0i = sfin[4 * q + 0], c1i = sfin[4 * q + 1];
        const int c2i = sfin[4 * q + 2], c3i = sfin[4 * q + 3];
        const float* r0 = cb + c0i * DIM;
        const float* r1 = cb + c1i * DIM;
        const float* r2 = cb + c2i * DIM;
        const float* r3 = cb + c3i * DIM;
        float* ob = out + (size_t)batch * (DIM * 1024) + hw0 + 4 * q;
        #pragma unroll 4
        for (int j = 0; j < 32; ++j) {
            const int d = dg * 32 + j;
            f32x4_t v; v.x = r0[d]; v.y = r1[d]; v.z = r2[d]; v.w = r3[d];
            *(f32x4_t*)(ob + (size_t)d * 1024) = v;
        }
    }
}

// ---- finalize loss ----
__global__ void vq_final(const float* __restrict__ loss_accum, float* __restrict__ out_loss) {
    *out_loss = 1.25f * (*loss_accum) / 16777216.f;
}

extern "C" void kernel_launch(void* const* d_in, const int* in_sizes, int n_in,
                              void* d_out, int out_size, void* d_ws, size_t ws_size,
                              hipStream_t stream) {
    const float* x  = (const float*)d_in[0];   // [64,256,32,32]
    const float* cb = (const float*)d_in[1];   // [1024,256]
    float* out = (float*)d_out;                // 16777216 + 1

    char* ws = (char*)d_ws;
    float* loss_accum = (float*)ws;                        // 4 B
    char*  cbsw       = ws + 1024;                         // 512 KB, A-frag order
    float* nh_ord     = (float*)(ws + 1024 + 512 * 1024);  // 4 KB

    hipMemsetAsync(loss_accum, 0, sizeof(float), stream);
    vq_prep<<<dim3(256), dim3(256), 0, stream>>>(cb, cbsw, nh_ord);
    vq_main<<<dim3(512), dim3(256), 0, stream>>>(x, cb, cbsw, nh_ord, out, loss_accum);
    vq_final<<<dim3(1), dim3(1), 0, stream>>>(loss_accum, out + 16777216);
}

// Round 8
// 177.320 us; speedup vs baseline: 1.0086x; 1.0086x over previous
//
#include <hip/hip_runtime.h>
#include <stdint.h>

// VectorQuantizer on MI355X (gfx950) — round 13b (R13 + sched_barrier hardening;
// R13's bench died at container level, no counters — ledger re-audited, one
// rule-#18 hazard fixed: ds_reads now fenced below the raw s_barrier).
//
// Structure (from R12/R13 post-mortems): 512 blocks x 4 waves; x STATIONARY in
// regs/AGPRs (16 B-frags per wave, loaded once, direct global->reg); codebook
// A-tiles streamed through a 4-slot x 16 KB LDS ring via global_load_lds(16B),
// staged 2 tiles ahead; per-iter {issue stage(mt+2); s_waitcnt vmcnt(8);
// s_barrier; sched_barrier; 16 ds_read + 2x8 MFMA chains; scan}. The counted
// vmcnt (T3/T4, m218) replaces R12's per-tile __syncthreads vmcnt(0) convoy
// (R12: 5600 cyc/tile measured vs 1700 cyc resource floor). Tail: dummy
// re-stages of tiles 0,1 into slots 0,1 keep the wait-count uniform; sfin
// overlays slot 2 (drained at iter 30, untouched by dummies).

#define DIM 256
#define AS1 __attribute__((address_space(1)))
#define AS3 __attribute__((address_space(3)))

typedef __attribute__((ext_vector_type(8)))  short bf16x8_t;   // MFMA A/B frag (4 VGPRs)
typedef __attribute__((ext_vector_type(4)))  float f32x4_t;
typedef __attribute__((ext_vector_type(16))) float f32x16_t;   // 32x32 C/D frag

__device__ __forceinline__ uint32_t f2bf(float f) {
    union { float f; uint32_t u; } v; v.f = f;
    uint32_t r = v.u + 0x7FFFu + ((v.u >> 16) & 1u);   // RNE
    return r >> 16;
}

// ---- prep: one wave per code. Emits (a) bf16 codebook in exact MFMA A-frag
// order: entry e=(mt*16+ks)*64+lane2 holds cb[mt*32+(lane2&31)][ks*16+(lane2>>5)*8+j],
// and (b) -0.5*||c||^2 in C/D-register order (nh_ord[mt*32 + half*16 + r]).
__global__ __launch_bounds__(256) void vq_prep(const float* __restrict__ cb,
                                               char* __restrict__ cbsw,
                                               float* __restrict__ nh_ord) {
    const int code = blockIdx.x * 4 + (threadIdx.x >> 6);
    const int l    = threadIdx.x & 63;               // holds d = 4l..4l+3
    const f32x4_t v = ((const f32x4_t*)(cb + code * DIM))[l];
    float sq = v.x * v.x + v.y * v.y + v.z * v.z + v.w * v.w;

    const int mt = code >> 5;
    const int ks = l >> 2;               // d/16
    const int hl = (l >> 1) & 1;         // (d%16)/8
    const uint32_t ebyte = (uint32_t)(((mt * 16 + ks) * 64 + (code & 31) + 32 * hl) * 16
                                      + (l & 1) * 8);
    uint2 o;
    o.x = f2bf(v.x) | (f2bf(v.y) << 16);
    o.y = f2bf(v.z) | (f2bf(v.w) << 16);
    *(uint2*)(cbsw + ebyte) = o;

    #pragma unroll
    for (int m = 32; m; m >>= 1) sq += __shfl_xor(sq, m);
    if (l == 0) {
        const int rw = code & 31;
        const int h4 = (rw >> 2) & 1;
        const int r  = (rw & 3) | ((rw >> 3) << 2);
        nh_ord[mt * 32 + h4 * 16 + r] = -0.5f * sq;
    }
}

// ---- main: 512 blocks x 256 threads; block = 128 hw rows; wave w owns rows
// w*32..w*32+31 and sweeps all 1024 codes (32 m-tiles through the 4-slot ring).
__global__ __launch_bounds__(256, 2) void vq_main(const float* __restrict__ x,
                                                  const float* __restrict__ cb,
                                                  const char* __restrict__ cbsw,
                                                  const float* __restrict__ nh_ord,
                                                  float* __restrict__ out,
                                                  float* __restrict__ loss_accum) {
    // 64 KB: 4 slots x 16 KB A-tile ring. sfin overlays slot 2 post-loop.
    __shared__ __align__(16) uint32_t shm[4 * 4096];

    const int t    = threadIdx.x;
    const int w    = t >> 6;
    const int lane = t & 63;
    const int col  = lane & 31;          // row within wave's 32
    const int hi   = lane >> 5;          // k-half (d-octet selector)
    const int n0   = blockIdx.x * 128;
    const int batch = n0 >> 10;
    const int hw0   = n0 & 1023;

    // ---- issue A tiles 0 and 1 now; they retire under the x-load drain.
    #pragma unroll
    for (int pt = 0; pt < 2; ++pt) {
        const char* s = cbsw + (size_t)pt * 16384 + w * 1024 + lane * 16;
        uint32_t* db = shm + pt * 4096;
        #pragma unroll
        for (int q = 0; q < 4; ++q)
            __builtin_amdgcn_global_load_lds(
                (const AS1 uint32_t*)(s + q * 4096),
                (AS3 uint32_t*)(db + q * 1024 + w * 256),   // +lane*16B by HW
                16, 0, 0);
    }

    // ---- x -> breg direct (no LDS round-trip). Lane holds rows w*32+col,
    // d = ks*16 + hi*8 + j. Per (ks,j) load: lanes 0-31 one 128B segment,
    // lanes 32-63 the d+8 segment. Also accumulates ||x||^2.
    float sq = 0.f;
    bf16x8_t breg[16];
    {
        const float* xp = x + (size_t)batch * (DIM * 1024) + (size_t)hi * 8 * 1024
                            + hw0 + w * 32 + col;
        #pragma unroll
        for (int ks = 0; ks < 16; ++ks) {
            const float* dp = xp + (size_t)ks * 16 * 1024;
            float a[8];
            #pragma unroll
            for (int j = 0; j < 8; ++j) {
                a[j] = dp[(size_t)j * 1024];
                sq += a[j] * a[j];
            }
            uint4 pk;
            pk.x = f2bf(a[0]) | (f2bf(a[1]) << 16);
            pk.y = f2bf(a[2]) | (f2bf(a[3]) << 16);
            pk.z = f2bf(a[4]) | (f2bf(a[5]) << 16);
            pk.w = f2bf(a[6]) | (f2bf(a[7]) << 16);
            union { uint4 u; bf16x8_t v; } cv; cv.u = pk;
            breg[ks] = cv.v;
        }
        #pragma unroll
        for (int m = 32; m; m >>= 1) sq += __shfl_xor(sq, m);
    }
    __syncthreads();   // vmcnt(0) drain: tiles 0,1 staged block-wide

    // ---- K-loop: 32 m-tiles; counted-vmcnt pipeline, never drains to 0.
    float best = -3.0e38f;
    int   bi = 0;

    #pragma unroll 1
    for (int mt = 0; mt < 32; ++mt) {
        // issue stage of tile (mt+2); tail (mt>=30) dummy-restages tiles 0,1
        // into slots 0,1 — keeps the wait count uniform, never read again.
        {
            const int st = (mt + 2) & 31;
            const char* s = cbsw + (size_t)st * 16384 + w * 1024 + lane * 16;
            uint32_t* db = shm + ((mt + 2) & 3) * 4096;
            #pragma unroll
            for (int q = 0; q < 4; ++q)
                __builtin_amdgcn_global_load_lds(
                    (const AS1 uint32_t*)(s + q * 4096),
                    (AS3 uint32_t*)(db + q * 1024 + w * 256),
                    16, 0, 0);
        }

        // oldest 4 (= stage(mt)) forced to retire; stages mt+1,mt+2 in flight.
        asm volatile("s_waitcnt vmcnt(8)" ::: "memory");
        __builtin_amdgcn_s_barrier();
        __builtin_amdgcn_sched_barrier(0);   // rule #18: pin ds_reads below

        const uint32_t* cur = shm + (mt & 3) * 4096;
        const f32x4_t* nhp = (const f32x4_t*)(nh_ord + mt * 32 + hi * 16);
        const f32x4_t h0 = nhp[0], h1 = nhp[1], h2 = nhp[2], h3 = nhp[3];

        // two independent 8-deep MFMA chains (alternating ks)
        f32x16_t c0, c1;
        #pragma unroll
        for (int r = 0; r < 4; ++r) {
            c0[r] = h0[r]; c0[4 + r] = h1[r]; c0[8 + r] = h2[r]; c0[12 + r] = h3[r];
            c1[r] = 0.f;   c1[4 + r] = 0.f;   c1[8 + r] = 0.f;   c1[12 + r] = 0.f;
        }
        #pragma unroll
        for (int ks = 0; ks < 16; ks += 2) {
            const bf16x8_t a0 = *(const bf16x8_t*)(cur + ks * 256 + lane * 4);
            const bf16x8_t a1 = *(const bf16x8_t*)(cur + (ks + 1) * 256 + lane * 4);
            c0 = __builtin_amdgcn_mfma_f32_32x32x16_bf16(a0, breg[ks], c0, 0, 0, 0);
            c1 = __builtin_amdgcn_mfma_f32_32x32x16_bf16(a1, breg[ks + 1], c1, 0, 0, 0);
        }

        // scan: codes in increasing order; strict > keeps the lowest index
        #pragma unroll
        for (int r = 0; r < 16; ++r) {
            const float v = c0[r] + c1[r];
            const int code = mt * 32 + hi * 4 + ((r & 3) + 8 * (r >> 2));
            if (v > best) { best = v; bi = code; }
        }
    }

    // ---- combine lane pairs (same row, disjoint code subsets) -> best-of-1024
    {
        const float ov = __shfl_xor(best, 32);
        const int   oi = __shfl_xor(bi, 32);
        if (ov > best || (ov == best && oi < bi)) { best = ov; bi = oi; }
    }

    // ---- publish indices into slot 2 (tile 30: drained at iter 30's wait;
    // tail dummies only touch slots 0,1; every wave past barrier 31 has
    // finished reading slot 2 at iter 30).
    int* sfin = (int*)(shm + 2 * 4096);
    if (lane < 32) sfin[w * 32 + lane] = bi;

    // ---- per-wave loss partial: lane pairs duplicate each row's best, so
    // sum(-best) over 64 lanes = -2*sum_rows(score); sq adds ||x||^2.
    {
        float ls = -best;
        #pragma unroll
        for (int m = 32; m; m >>= 1) ls += __shfl_xor(ls, m);
        if (lane == 0) atomicAdd(loss_accum, ls + sq);
    }
    __syncthreads();   // full drain (incl. dummy stages) + sfin visible

    // ---- epilogue: gather fp32 codebook rows, dwordx4 stores along hw
    {
        const int q  = t & 31;     // rows 4q..4q+3 of 128
        const int dg = t >> 5;     // 0..7 -> d in [dg*32, dg*32+32)
        const int c0i = sfin[4 * q + 0], c1i = sfin[4 * q + 1];
        const int c2i = sfin[4 * q + 2], c3i = sfin[4 * q + 3];
        const float* r0 = cb + c0i * DIM;
        const float* r1 = cb + c1i * DIM;
        const float* r2 = cb + c2i * DIM;
        const float* r3 = cb + c3i * DIM;
        float* ob = out + (size_t)batch * (DIM * 1024) + hw0 + 4 * q;
        #pragma unroll 4
        for (int j = 0; j < 32; ++j) {
            const int d = dg * 32 + j;
            f32x4_t v; v.x = r0[d]; v.y = r1[d]; v.z = r2[d]; v.w = r3[d];
            *(f32x4_t*)(ob + (size_t)d * 1024) = v;
        }
    }
}

// ---- finalize loss ----
__global__ void vq_final(const float* __restrict__ loss_accum, float* __restrict__ out_loss) {
    *out_loss = 1.25f * (*loss_accum) / 16777216.f;
}

extern "C" void kernel_launch(void* const* d_in, const int* in_sizes, int n_in,
                              void* d_out, int out_size, void* d_ws, size_t ws_size,
                              hipStream_t stream) {
    const float* x  = (const float*)d_in[0];   // [64,256,32,32]
    const float* cb = (const float*)d_in[1];   // [1024,256]
    float* out = (float*)d_out;                // 16777216 + 1

    char* ws = (char*)d_ws;
    float* loss_accum = (float*)ws;                        // 4 B
    char*  cbsw       = ws + 1024;                         // 512 KB, A-frag order
    float* nh_ord     = (float*)(ws + 1024 + 512 * 1024);  // 4 KB

    hipMemsetAsync(loss_accum, 0, sizeof(float), stream);
    vq_prep<<<dim3(256), dim3(256), 0, stream>>>(cb, cbsw, nh_ord);
    vq_main<<<dim3(512), dim3(256), 0, stream>>>(x, cb, cbsw, nh_ord, out, loss_accum);
    vq_final<<<dim3(1), dim3(1), 0, stream>>>(loss_accum, out + 16777216);
}